// Round 1
// baseline (3687.008 us; speedup 1.0000x reference)
//
#include <hip/hip_runtime.h>

// MixLlamaMLP: y = (silu(x@Wg) * (x@Wu)) @ Wd
// B=4 S=2048 H=4096 I=11008, M = B*S = 8192. fp32 in/out, bf16 MFMA compute.
#define M_ 8192
#define H_ 4096
#define I_ 11008

typedef __bf16  bf16x8  __attribute__((ext_vector_type(8)));
typedef float   floatx4 __attribute__((ext_vector_type(4)));

__device__ __forceinline__ unsigned short f2bf(float f) {
  // round-to-nearest-even fp32 -> bf16 (no NaN handling needed; inputs tame)
  unsigned int u = __builtin_bit_cast(unsigned int, f);
  u += 0x7fffu + ((u >> 16) & 1u);
  return (unsigned short)(u >> 16);
}

__device__ __forceinline__ void gl_lds16(const unsigned short* g, unsigned short* l) {
  // async global->LDS, 16B per lane; LDS dest = wave-uniform base + lane*16
  __builtin_amdgcn_global_load_lds(
      (__attribute__((address_space(1))) void*)g,
      (__attribute__((address_space(3))) void*)l,
      16, 0, 0);
}

// ---------------- conversion kernels ----------------

__global__ void cvt_x_kernel(const float4* __restrict__ in, ushort4* __restrict__ out) {
  int i = blockIdx.x * blockDim.x + threadIdx.x;
  float4 v = in[i];
  out[i] = make_ushort4(f2bf(v.x), f2bf(v.y), f2bf(v.z), f2bf(v.w));
}

// in: fp32 [R][C] row-major  ->  out: bf16 [C][R] row-major (transpose+convert)
__global__ void transpose_cvt_kernel(const float* __restrict__ in,
                                     unsigned short* __restrict__ out,
                                     int R, int C) {
  __shared__ float tile[32][33];
  int tx = threadIdx.x & 31;
  int ty = threadIdx.x >> 5;            // 0..7
  int c0 = blockIdx.x * 32;
  int r0 = blockIdx.y * 32;
#pragma unroll
  for (int i = 0; i < 32; i += 8)
    tile[ty + i][tx] = in[(size_t)(r0 + ty + i) * C + (c0 + tx)];
  __syncthreads();
#pragma unroll
  for (int i = 0; i < 32; i += 8)
    out[(size_t)(c0 + ty + i) * R + (r0 + tx)] = f2bf(tile[tx][ty + i]);
}

// ---------------- fused gate+up GEMM ----------------
// C_act[m][n] = silu(sum_k X[m][k]*WgT[n][k]) * (sum_k X[m][k]*WuT[n][k])
// X bf16 [M][H], WgT/WuT bf16 [I][H], Act bf16 [M][I]
__global__ __launch_bounds__(256, 2) void gemm_gateup_kernel(
    const unsigned short* __restrict__ Xb,
    const unsigned short* __restrict__ WgT,
    const unsigned short* __restrict__ WuT,
    unsigned short* __restrict__ Act) {
  __shared__ alignas(16) unsigned short sA[128 * 32];
  __shared__ alignas(16) unsigned short sG[128 * 32];
  __shared__ alignas(16) unsigned short sU[128 * 32];

  const int tid  = threadIdx.x;
  const int lane = tid & 63;
  const int quad = lane >> 4;
  const int lr   = lane & 15;
  const int wave = tid >> 6;
  const int wm   = wave >> 1;  // 0..1
  const int wn   = wave & 1;   // 0..1

  const int m0 = blockIdx.y * 128;
  const int n0 = blockIdx.x * 128;

  // staging: tile is 128 rows x 32 bf16 = 128 x 64B; 16B chunks: flat = row*4+chunk
  const int row0 = tid >> 2, ch0 = tid & 3;
  const int row1 = (256 + tid) >> 2, ch1 = tid & 3;  // (256+tid)&3 == tid&3

  const unsigned short* gA0 = Xb  + (size_t)(m0 + row0) * H_ + ch0 * 8;
  const unsigned short* gA1 = Xb  + (size_t)(m0 + row1) * H_ + ch1 * 8;
  const unsigned short* gG0 = WgT + (size_t)(n0 + row0) * H_ + ch0 * 8;
  const unsigned short* gG1 = WgT + (size_t)(n0 + row1) * H_ + ch1 * 8;
  const unsigned short* gU0 = WuT + (size_t)(n0 + row0) * H_ + ch0 * 8;
  const unsigned short* gU1 = WuT + (size_t)(n0 + row1) * H_ + ch1 * 8;
  unsigned short* lA0 = sA + (size_t)tid * 8;
  unsigned short* lA1 = sA + (size_t)(256 + tid) * 8;
  unsigned short* lG0 = sG + (size_t)tid * 8;
  unsigned short* lG1 = sG + (size_t)(256 + tid) * 8;
  unsigned short* lU0 = sU + (size_t)tid * 8;
  unsigned short* lU1 = sU + (size_t)(256 + tid) * 8;

  floatx4 accG[4][4] = {};
  floatx4 accU[4][4] = {};

  for (int k0 = 0; k0 < H_; k0 += 32) {
    gl_lds16(gA0 + k0, lA0);
    gl_lds16(gA1 + k0, lA1);
    gl_lds16(gG0 + k0, lG0);
    gl_lds16(gG1 + k0, lG1);
    gl_lds16(gU0 + k0, lU0);
    gl_lds16(gU1 + k0, lU1);
    __syncthreads();  // drains vmcnt(0): staging complete

    bf16x8 af[4], bg[4], bu[4];
#pragma unroll
    for (int i = 0; i < 4; ++i)
      af[i] = *(const bf16x8*)(sA + ((wm * 64 + i * 16 + lr) * 32 + quad * 8));
#pragma unroll
    for (int j = 0; j < 4; ++j) {
      bg[j] = *(const bf16x8*)(sG + ((wn * 64 + j * 16 + lr) * 32 + quad * 8));
      bu[j] = *(const bf16x8*)(sU + ((wn * 64 + j * 16 + lr) * 32 + quad * 8));
    }
#pragma unroll
    for (int i = 0; i < 4; ++i)
#pragma unroll
      for (int j = 0; j < 4; ++j) {
        accG[i][j] = __builtin_amdgcn_mfma_f32_16x16x32_bf16(af[i], bg[j], accG[i][j], 0, 0, 0);
        accU[i][j] = __builtin_amdgcn_mfma_f32_16x16x32_bf16(af[i], bu[j], accU[i][j], 0, 0, 0);
      }
    __syncthreads();  // all waves done reading LDS before next stage
  }

  // epilogue: silu(g)*u -> bf16 Act. C/D layout: row = quad*4+r, col = lr
#pragma unroll
  for (int i = 0; i < 4; ++i) {
    const int mbase = m0 + wm * 64 + i * 16 + quad * 4;
#pragma unroll
    for (int j = 0; j < 4; ++j) {
      const int ncol = n0 + wn * 64 + j * 16 + lr;
#pragma unroll
      for (int r = 0; r < 4; ++r) {
        float g = accG[i][j][r];
        float u = accU[i][j][r];
        float s = g / (1.0f + __expf(-g));
        Act[(size_t)(mbase + r) * I_ + ncol] = f2bf(s * u);
      }
    }
  }
}

// ---------------- down GEMM ----------------
// Y[m][n] = sum_k Act[m][k] * WdT[n][k];  Act bf16 [M][I], WdT bf16 [H][I], Y fp32 [M][H]
__global__ __launch_bounds__(256, 2) void gemm_down_kernel(
    const unsigned short* __restrict__ Ab,
    const unsigned short* __restrict__ WdT,
    float* __restrict__ Y) {
  __shared__ alignas(16) unsigned short sA[128 * 32];
  __shared__ alignas(16) unsigned short sB[128 * 32];

  const int tid  = threadIdx.x;
  const int lane = tid & 63;
  const int quad = lane >> 4;
  const int lr   = lane & 15;
  const int wave = tid >> 6;
  const int wm   = wave >> 1;
  const int wn   = wave & 1;

  const int m0 = blockIdx.y * 128;
  const int n0 = blockIdx.x * 128;

  const int row0 = tid >> 2, ch0 = tid & 3;
  const int row1 = (256 + tid) >> 2;

  const unsigned short* gA0 = Ab  + (size_t)(m0 + row0) * I_ + ch0 * 8;
  const unsigned short* gA1 = Ab  + (size_t)(m0 + row1) * I_ + ch0 * 8;
  const unsigned short* gB0 = WdT + (size_t)(n0 + row0) * I_ + ch0 * 8;
  const unsigned short* gB1 = WdT + (size_t)(n0 + row1) * I_ + ch0 * 8;
  unsigned short* lA0 = sA + (size_t)tid * 8;
  unsigned short* lA1 = sA + (size_t)(256 + tid) * 8;
  unsigned short* lB0 = sB + (size_t)tid * 8;
  unsigned short* lB1 = sB + (size_t)(256 + tid) * 8;

  floatx4 acc[4][4] = {};

  for (int k0 = 0; k0 < I_; k0 += 32) {
    gl_lds16(gA0 + k0, lA0);
    gl_lds16(gA1 + k0, lA1);
    gl_lds16(gB0 + k0, lB0);
    gl_lds16(gB1 + k0, lB1);
    __syncthreads();

    bf16x8 af[4], bf[4];
#pragma unroll
    for (int i = 0; i < 4; ++i)
      af[i] = *(const bf16x8*)(sA + ((wm * 64 + i * 16 + lr) * 32 + quad * 8));
#pragma unroll
    for (int j = 0; j < 4; ++j)
      bf[j] = *(const bf16x8*)(sB + ((wn * 64 + j * 16 + lr) * 32 + quad * 8));
#pragma unroll
    for (int i = 0; i < 4; ++i)
#pragma unroll
      for (int j = 0; j < 4; ++j)
        acc[i][j] = __builtin_amdgcn_mfma_f32_16x16x32_bf16(af[i], bf[j], acc[i][j], 0, 0, 0);
    __syncthreads();
  }

#pragma unroll
  for (int i = 0; i < 4; ++i) {
    const int mbase = m0 + wm * 64 + i * 16 + quad * 4;
#pragma unroll
    for (int j = 0; j < 4; ++j) {
      const int ncol = n0 + wn * 64 + j * 16 + lr;
#pragma unroll
      for (int r = 0; r < 4; ++r)
        Y[(size_t)(mbase + r) * H_ + ncol] = acc[i][j][r];
    }
  }
}

// ---------------- launch ----------------

extern "C" void kernel_launch(void* const* d_in, const int* in_sizes, int n_in,
                              void* d_out, int out_size, void* d_ws, size_t ws_size,
                              hipStream_t stream) {
  const float* x  = (const float*)d_in[0];
  const float* wg = (const float*)d_in[1];
  const float* wu = (const float*)d_in[2];
  const float* wd = (const float*)d_in[3];
  float* out = (float*)d_out;

  // workspace layout (bytes): all bf16 (ushort) buffers
  char* ws = (char*)d_ws;
  unsigned short* xb  = (unsigned short*)(ws);                      // [M][H]   67,108,864 B
  unsigned short* wgT = (unsigned short*)(ws + 67108864);           // [I][H]   90,177,536 B
  unsigned short* wuT = (unsigned short*)(ws + 157286400);          // [I][H]   90,177,536 B
  unsigned short* wdT = (unsigned short*)(ws + 247463936);          // [H][I]   90,177,536 B
  unsigned short* act = (unsigned short*)(ws + 337641472);          // [M][I]  180,355,072 B
  // total 517,996,544 B

  // x fp32 -> bf16 (same layout)
  cvt_x_kernel<<<(M_ * H_ / 4) / 256, 256, 0, stream>>>((const float4*)x, (ushort4*)xb);
  // w_gate/w_up fp32 [H][I] -> bf16 [I][H]
  transpose_cvt_kernel<<<dim3(I_ / 32, H_ / 32), 256, 0, stream>>>(wg, wgT, H_, I_);
  transpose_cvt_kernel<<<dim3(I_ / 32, H_ / 32), 256, 0, stream>>>(wu, wuT, H_, I_);
  // w_down fp32 [I][H] -> bf16 [H][I]
  transpose_cvt_kernel<<<dim3(H_ / 32, I_ / 32), 256, 0, stream>>>(wd, wdT, I_, H_);

  // fused gate+up GEMM + silu*mul epilogue -> act
  gemm_gateup_kernel<<<dim3(I_ / 128, M_ / 128), 256, 0, stream>>>(xb, wgT, wuT, act);
  // down GEMM -> out
  gemm_down_kernel<<<dim3(H_ / 128, M_ / 128), 256, 0, stream>>>(act, wdT, out);
}

// Round 2
// 3334.031 us; speedup vs baseline: 1.1059x; 1.1059x over previous
//
#include <hip/hip_runtime.h>

// MixLlamaMLP: y = (silu(x@Wg) * (x@Wu)) @ Wd
// B=4 S=2048 H=4096 I=11008, M = B*S = 8192. fp32 in/out, bf16 MFMA compute.
// R2: LLC-aware block swizzle on both GEMMs (R1 showed 29x HBM over-fetch).
#define M_ 8192
#define H_ 4096
#define I_ 11008

typedef __bf16  bf16x8  __attribute__((ext_vector_type(8)));
typedef float   floatx4 __attribute__((ext_vector_type(4)));

__device__ __forceinline__ unsigned short f2bf(float f) {
  unsigned int u = __builtin_bit_cast(unsigned int, f);
  u += 0x7fffu + ((u >> 16) & 1u);
  return (unsigned short)(u >> 16);
}

__device__ __forceinline__ void gl_lds16(const unsigned short* g, unsigned short* l) {
  __builtin_amdgcn_global_load_lds(
      (__attribute__((address_space(1))) void*)g,
      (__attribute__((address_space(3))) void*)l,
      16, 0, 0);
}

// ---------------- conversion kernels ----------------

__global__ void cvt_x_kernel(const float4* __restrict__ in, ushort4* __restrict__ out) {
  int i = blockIdx.x * blockDim.x + threadIdx.x;
  float4 v = in[i];
  out[i] = make_ushort4(f2bf(v.x), f2bf(v.y), f2bf(v.z), f2bf(v.w));
}

// in: fp32 [R][C] row-major  ->  out: bf16 [C][R] row-major (transpose+convert)
__global__ void transpose_cvt_kernel(const float* __restrict__ in,
                                     unsigned short* __restrict__ out,
                                     int R, int C) {
  __shared__ float tile[32][33];
  int tx = threadIdx.x & 31;
  int ty = threadIdx.x >> 5;            // 0..7
  int c0 = blockIdx.x * 32;
  int r0 = blockIdx.y * 32;
#pragma unroll
  for (int i = 0; i < 32; i += 8)
    tile[ty + i][tx] = in[(size_t)(r0 + ty + i) * C + (c0 + tx)];
  __syncthreads();
#pragma unroll
  for (int i = 0; i < 32; i += 8)
    out[(size_t)(c0 + ty + i) * R + (r0 + tx)] = f2bf(tile[tx][ty + i]);
}

// ---------------- fused gate+up GEMM ----------------
// Act[m][n] = silu(X@WgT') * (X@WuT');  X bf16 [M][H], WgT/WuT bf16 [I][H], Act bf16 [M][I]
// 1D grid, swizzled: groups of (all 64 m-tiles) x GN n-tiles, m-fastest.
// Keeps X (67MB) LLC-resident across the whole kernel; weights streamed once.
__global__ __launch_bounds__(256, 2) void gemm_gateup_kernel(
    const unsigned short* __restrict__ Xb,
    const unsigned short* __restrict__ WgT,
    const unsigned short* __restrict__ WuT,
    unsigned short* __restrict__ Act) {
  __shared__ alignas(16) unsigned short sA[128 * 32];
  __shared__ alignas(16) unsigned short sG[128 * 32];
  __shared__ alignas(16) unsigned short sU[128 * 32];

  const int tid  = threadIdx.x;
  const int lane = tid & 63;
  const int quad = lane >> 4;
  const int lr   = lane & 15;
  const int wave = tid >> 6;
  const int wm   = wave >> 1;  // 0..1
  const int wn   = wave & 1;   // 0..1

  // swizzle: NM=64 m-tiles, NN=86 n-tiles, GN=8
  const int NM = M_ / 128;              // 64
  const int GN = 8;
  const int pid   = blockIdx.x;
  const int group = pid / (NM * GN);
  const int rem   = pid - group * (NM * GN);
  const int m0 = (rem % NM) * 128;
  const int n0 = (group * GN + rem / NM) * 128;

  const int row0 = tid >> 2, ch0 = tid & 3;
  const int row1 = (256 + tid) >> 2;

  const unsigned short* gA0 = Xb  + (size_t)(m0 + row0) * H_ + ch0 * 8;
  const unsigned short* gA1 = Xb  + (size_t)(m0 + row1) * H_ + ch0 * 8;
  const unsigned short* gG0 = WgT + (size_t)(n0 + row0) * H_ + ch0 * 8;
  const unsigned short* gG1 = WgT + (size_t)(n0 + row1) * H_ + ch0 * 8;
  const unsigned short* gU0 = WuT + (size_t)(n0 + row0) * H_ + ch0 * 8;
  const unsigned short* gU1 = WuT + (size_t)(n0 + row1) * H_ + ch0 * 8;
  unsigned short* lA0 = sA + (size_t)tid * 8;
  unsigned short* lA1 = sA + (size_t)(256 + tid) * 8;
  unsigned short* lG0 = sG + (size_t)tid * 8;
  unsigned short* lG1 = sG + (size_t)(256 + tid) * 8;
  unsigned short* lU0 = sU + (size_t)tid * 8;
  unsigned short* lU1 = sU + (size_t)(256 + tid) * 8;

  floatx4 accG[4][4] = {};
  floatx4 accU[4][4] = {};

  for (int k0 = 0; k0 < H_; k0 += 32) {
    gl_lds16(gA0 + k0, lA0);
    gl_lds16(gA1 + k0, lA1);
    gl_lds16(gG0 + k0, lG0);
    gl_lds16(gG1 + k0, lG1);
    gl_lds16(gU0 + k0, lU0);
    gl_lds16(gU1 + k0, lU1);
    __syncthreads();

    bf16x8 af[4], bg[4], bu[4];
#pragma unroll
    for (int i = 0; i < 4; ++i)
      af[i] = *(const bf16x8*)(sA + ((wm * 64 + i * 16 + lr) * 32 + quad * 8));
#pragma unroll
    for (int j = 0; j < 4; ++j) {
      bg[j] = *(const bf16x8*)(sG + ((wn * 64 + j * 16 + lr) * 32 + quad * 8));
      bu[j] = *(const bf16x8*)(sU + ((wn * 64 + j * 16 + lr) * 32 + quad * 8));
    }
#pragma unroll
    for (int i = 0; i < 4; ++i)
#pragma unroll
      for (int j = 0; j < 4; ++j) {
        accG[i][j] = __builtin_amdgcn_mfma_f32_16x16x32_bf16(af[i], bg[j], accG[i][j], 0, 0, 0);
        accU[i][j] = __builtin_amdgcn_mfma_f32_16x16x32_bf16(af[i], bu[j], accU[i][j], 0, 0, 0);
      }
    __syncthreads();
  }

#pragma unroll
  for (int i = 0; i < 4; ++i) {
    const int mbase = m0 + wm * 64 + i * 16 + quad * 4;
#pragma unroll
    for (int j = 0; j < 4; ++j) {
      const int ncol = n0 + wn * 64 + j * 16 + lr;
#pragma unroll
      for (int r = 0; r < 4; ++r) {
        float g = accG[i][j][r];
        float u = accU[i][j][r];
        float s = g / (1.0f + __expf(-g));
        Act[(size_t)(mbase + r) * I_ + ncol] = f2bf(s * u);
      }
    }
  }
}

// ---------------- down GEMM ----------------
// Y[m][n] = Act @ WdT';  Act bf16 [M][I], WdT bf16 [H][I], Y fp32 [M][H]
// swizzle: groups of GM m-tiles x (all 32 n-tiles), n-fastest.
// Keeps WdT (90MB) LLC-resident for the whole kernel; Act streamed once.
__global__ __launch_bounds__(256, 2) void gemm_down_kernel(
    const unsigned short* __restrict__ Ab,
    const unsigned short* __restrict__ WdT,
    float* __restrict__ Y) {
  __shared__ alignas(16) unsigned short sA[128 * 32];
  __shared__ alignas(16) unsigned short sB[128 * 32];

  const int tid  = threadIdx.x;
  const int lane = tid & 63;
  const int quad = lane >> 4;
  const int lr   = lane & 15;
  const int wave = tid >> 6;
  const int wm   = wave >> 1;
  const int wn   = wave & 1;

  const int NN = H_ / 128;              // 32
  const int GM = 16;
  const int pid   = blockIdx.x;
  const int group = pid / (NN * GM);
  const int rem   = pid - group * (NN * GM);
  const int n0 = (rem % NN) * 128;
  const int m0 = (group * GM + rem / NN) * 128;

  const int row0 = tid >> 2, ch0 = tid & 3;
  const int row1 = (256 + tid) >> 2;

  const unsigned short* gA0 = Ab  + (size_t)(m0 + row0) * I_ + ch0 * 8;
  const unsigned short* gA1 = Ab  + (size_t)(m0 + row1) * I_ + ch0 * 8;
  const unsigned short* gB0 = WdT + (size_t)(n0 + row0) * I_ + ch0 * 8;
  const unsigned short* gB1 = WdT + (size_t)(n0 + row1) * I_ + ch0 * 8;
  unsigned short* lA0 = sA + (size_t)tid * 8;
  unsigned short* lA1 = sA + (size_t)(256 + tid) * 8;
  unsigned short* lB0 = sB + (size_t)tid * 8;
  unsigned short* lB1 = sB + (size_t)(256 + tid) * 8;

  floatx4 acc[4][4] = {};

  for (int k0 = 0; k0 < I_; k0 += 32) {
    gl_lds16(gA0 + k0, lA0);
    gl_lds16(gA1 + k0, lA1);
    gl_lds16(gB0 + k0, lB0);
    gl_lds16(gB1 + k0, lB1);
    __syncthreads();

    bf16x8 af[4], bf[4];
#pragma unroll
    for (int i = 0; i < 4; ++i)
      af[i] = *(const bf16x8*)(sA + ((wm * 64 + i * 16 + lr) * 32 + quad * 8));
#pragma unroll
    for (int j = 0; j < 4; ++j)
      bf[j] = *(const bf16x8*)(sB + ((wn * 64 + j * 16 + lr) * 32 + quad * 8));
#pragma unroll
    for (int i = 0; i < 4; ++i)
#pragma unroll
      for (int j = 0; j < 4; ++j)
        acc[i][j] = __builtin_amdgcn_mfma_f32_16x16x32_bf16(af[i], bf[j], acc[i][j], 0, 0, 0);
    __syncthreads();
  }

#pragma unroll
  for (int i = 0; i < 4; ++i) {
    const int mbase = m0 + wm * 64 + i * 16 + quad * 4;
#pragma unroll
    for (int j = 0; j < 4; ++j) {
      const int ncol = n0 + wn * 64 + j * 16 + lr;
#pragma unroll
      for (int r = 0; r < 4; ++r)
        Y[(size_t)(mbase + r) * H_ + ncol] = acc[i][j][r];
    }
  }
}

// ---------------- launch ----------------

extern "C" void kernel_launch(void* const* d_in, const int* in_sizes, int n_in,
                              void* d_out, int out_size, void* d_ws, size_t ws_size,
                              hipStream_t stream) {
  const float* x  = (const float*)d_in[0];
  const float* wg = (const float*)d_in[1];
  const float* wu = (const float*)d_in[2];
  const float* wd = (const float*)d_in[3];
  float* out = (float*)d_out;

  char* ws = (char*)d_ws;
  unsigned short* xb  = (unsigned short*)(ws);                      // [M][H]   67,108,864 B
  unsigned short* wgT = (unsigned short*)(ws + 67108864);           // [I][H]   90,177,536 B
  unsigned short* wuT = (unsigned short*)(ws + 157286400);          // [I][H]   90,177,536 B
  unsigned short* wdT = (unsigned short*)(ws + 247463936);          // [H][I]   90,177,536 B
  unsigned short* act = (unsigned short*)(ws + 337641472);          // [M][I]  180,355,072 B

  cvt_x_kernel<<<(M_ * H_ / 4) / 256, 256, 0, stream>>>((const float4*)x, (ushort4*)xb);
  transpose_cvt_kernel<<<dim3(I_ / 32, H_ / 32), 256, 0, stream>>>(wg, wgT, H_, I_);
  transpose_cvt_kernel<<<dim3(I_ / 32, H_ / 32), 256, 0, stream>>>(wu, wuT, H_, I_);
  transpose_cvt_kernel<<<dim3(H_ / 32, I_ / 32), 256, 0, stream>>>(wd, wdT, I_, H_);

  gemm_gateup_kernel<<<(M_ / 128) * (I_ / 128), 256, 0, stream>>>(xb, wgT, wuT, act);
  gemm_down_kernel<<<(M_ / 128) * (H_ / 128), 256, 0, stream>>>(act, wdT, out);
}